// Round 3
// baseline (1557.003 us; speedup 1.0000x reference)
//
#include <hip/hip_runtime.h>

#define Nn 50000
#define Rr 16
#define Dd 64
#define Fin 128
#define Ee 100000

typedef __attribute__((ext_vector_type(8))) short short8;
typedef __attribute__((ext_vector_type(4))) float f32x4;
typedef unsigned short ushort_t;

__device__ inline ushort_t f2bf(float x) {
  union { float f; unsigned u; } v; v.f = x;
  unsigned u = v.u;
  return (ushort_t)((u + 0x7FFFu + ((u >> 16) & 1u)) >> 16);  // RNE
}
__device__ inline float bf2f(ushort_t h) {
  union { unsigned u; float f; } v; v.u = ((unsigned)h) << 16; return v.f;
}

// ---------------- init: emb0 = x @ ent_emb, bf16 out ----------------
__global__ __launch_bounds__(256) void init_gemm(const float* __restrict__ x,
                                                 const float* __restrict__ w,
                                                 ushort_t* __restrict__ out) {
  int wave = threadIdx.x >> 6, lane = threadIdx.x & 63;
  int row = blockIdx.x * 4 + wave;
  if (row >= Nn) return;
  const float* xr = x + (long)row * Fin;
  float acc = 0.f;
#pragma unroll 8
  for (int k = 0; k < Fin; ++k)
    acc = fmaf(xr[k], w[k * Dd + lane], acc);
  out[row * Dd + lane] = f2bf(acc);
}

// ---------------- CSR build ----------------
__global__ __launch_bounds__(256) void hist_k(const int* __restrict__ erow,
                                              int* __restrict__ cnt) {
  int e = blockIdx.x * 256 + threadIdx.x;
  int r = blockIdx.y;
  if (e < Ee) atomicAdd(&cnt[erow[r * Ee + e]], 1);
}

// parallel scan, 3 kernels: block-reduce, scan partials, block-scan+apply
#define SCAN_NB ((Nn + 255) / 256)  // 196
__global__ __launch_bounds__(256) void scan1_k(const int* __restrict__ cnt,
                                               int* __restrict__ bsum) {
  __shared__ int ls[256];
  int t = threadIdx.x, i = blockIdx.x * 256 + t;
  int v = (i < Nn) ? cnt[i] : 0;
  ls[t] = v;
  __syncthreads();
  for (int off = 128; off >= 1; off >>= 1) {
    if (t < off) ls[t] += ls[t + off];
    __syncthreads();
  }
  if (t == 0) bsum[blockIdx.x] = ls[0];
}

__global__ __launch_bounds__(256) void scan2_k(int* __restrict__ bsum) {
  __shared__ int ls[256];
  int t = threadIdx.x;
  int v = (t < SCAN_NB) ? bsum[t] : 0;
  ls[t] = v;
  __syncthreads();
  for (int off = 1; off < 256; off <<= 1) {
    int x = (t >= off) ? ls[t - off] : 0;
    __syncthreads();
    ls[t] += x;
    __syncthreads();
  }
  if (t < SCAN_NB) bsum[t] = ls[t] - v;  // exclusive
}

__global__ __launch_bounds__(256) void scan3_k(int* __restrict__ cnt,
                                               const int* __restrict__ bsum,
                                               int* __restrict__ offs) {
  __shared__ int ls[256];
  int t = threadIdx.x, i = blockIdx.x * 256 + t;
  int v = (i < Nn) ? cnt[i] : 0;
  ls[t] = v;
  __syncthreads();
  for (int off = 1; off < 256; off <<= 1) {
    int x = (t >= off) ? ls[t - off] : 0;
    __syncthreads();
    ls[t] += x;
    __syncthreads();
  }
  int excl = ls[t] - v + bsum[blockIdx.x];
  if (i < Nn) {
    offs[i] = excl;
    cnt[i] = excl;  // becomes cursor
  }
  if (i == Nn - 1) offs[Nn] = Rr * Ee;
}

__global__ __launch_bounds__(256) void scatter_k(const int* __restrict__ erow,
                                                 const int* __restrict__ ecol,
                                                 const float* __restrict__ ev,
                                                 int* __restrict__ cursor,
                                                 uint2* __restrict__ ed) {
  int e = blockIdx.x * 256 + threadIdx.x;
  int r = blockIdx.y;
  if (e >= Ee) return;
  long idx = (long)r * Ee + e;
  int row = erow[idx];
  int pos = atomicAdd(&cursor[row], 1);
  ed[pos] = make_uint2(((unsigned)r << 16) | (unsigned)ecol[idx],
                       __float_as_uint(ev[idx]));
}

// ---------------- W -> bf16 ----------------
__global__ __launch_bounds__(256) void convw_k(const float* __restrict__ rel,
                                               ushort_t* __restrict__ wbf) {
  int i = blockIdx.x * 256 + threadIdx.x;
  if (i < 2 * Rr * Dd * Dd) wbf[i] = f2bf(rel[i]);
}

// ---------------- fused layer: gather emb into LDS Z, then MFMA transform ----
// Block = 16 rows. Phase 1: Z[row][r][d] += val*emb[col][d]  (LDS f32, ds_add)
// Phase 2: out[16 rows][64] = Z[16][1024] @ Wcat[64][1024]^T  (MFMA, K=1024)
#define PITCHF 1028  // f32 pitch (floats): +4 breaks bank alignment
#define PITCHB 1032  // bf16 pitch (shorts)
__global__ __launch_bounds__(256) void layer_k(const ushort_t* __restrict__ emb,
                                               const ushort_t* __restrict__ wl,
                                               const int* __restrict__ offs,
                                               const uint2* __restrict__ ed,
                                               ushort_t* __restrict__ embout,
                                               float* __restrict__ finout,
                                               int fin) {
  __shared__ float accf[16 * PITCHF];  // 65792 B
  __shared__ float ssp[4 * 16];
  const int tid = threadIdx.x;
  const int wave = tid >> 6, lane = tid & 63;
  const int nt = lane & 15, quad = lane >> 4;
  const int row0 = blockIdx.x * 16;

  // zero LDS
  for (int i = tid; i < 16 * PITCHF; i += 256) accf[i] = 0.f;
  __syncthreads();

  // ---- phase 1: per-wave gather (wave owns 4 rows) ----
  for (int rr = 0; rr < 4; ++rr) {
    const int rl = wave * 4 + rr;
    const int row = row0 + rl;
    const int s = offs[row], e = offs[row + 1];
    float* arow = accf + rl * PITCHF;
    int i = s;
    const int e8 = s + ((e - s) & ~7);
    for (; i < e8; i += 8) {
      uint2 q[8];
      float y[8];
#pragma unroll
      for (int j = 0; j < 8; ++j) q[j] = ed[i + j];
#pragma unroll
      for (int j = 0; j < 8; ++j)
        y[j] = bf2f(emb[(q[j].x & 0xFFFFu) * 64u + lane]);
#pragma unroll
      for (int j = 0; j < 8; ++j)
        atomicAdd(&arow[(q[j].x >> 16) * 64u + lane],
                  __uint_as_float(q[j].y) * y[j]);
    }
    for (; i < e; ++i) {
      uint2 q = ed[i];
      float y = bf2f(emb[(q.x & 0xFFFFu) * 64u + lane]);
      atomicAdd(&arow[(q.x >> 16) * 64u + lane], __uint_as_float(q.y) * y);
    }
  }
  __syncthreads();

  // ---- phase 1.5: in-place f32 -> bf16 (chunked, barrier-safe) ----
  ushort_t* accb = (ushort_t*)accf;
  for (int c = 0; c < 4; ++c) {
    float v[16];
#pragma unroll
    for (int j = 0; j < 16; ++j) {
      int idx = c * 4096 + j * 256 + tid;
      v[j] = accf[(idx >> 10) * PITCHF + (idx & 1023)];
    }
    __syncthreads();
#pragma unroll
    for (int j = 0; j < 16; ++j) {
      int idx = c * 4096 + j * 256 + tid;
      accb[(idx >> 10) * PITCHB + (idx & 1023)] = f2bf(v[j]);
    }
    __syncthreads();
  }

  // ---- phase 2: MFMA. wave handles output cols [wave*16, wave*16+16) ----
  f32x4 c0 = {0.f, 0.f, 0.f, 0.f}, c1 = c0, c2 = c0, c3 = c0;
  for (int cc = 0; cc < 32; cc += 4) {
    int k0 = cc * 32 + quad * 8;
    short8 a0 = *(const short8*)(accb + nt * PITCHB + k0);
    short8 a1 = *(const short8*)(accb + nt * PITCHB + k0 + 32);
    short8 a2 = *(const short8*)(accb + nt * PITCHB + k0 + 64);
    short8 a3 = *(const short8*)(accb + nt * PITCHB + k0 + 96);
    const ushort_t* wb = wl + (unsigned)(wave * 16 + nt) * 64u;
    short8 b0 = *(const short8*)(wb + (unsigned)(k0 >> 6) * 4096u + (k0 & 63));
    int k1 = k0 + 32;
    short8 b1 = *(const short8*)(wb + (unsigned)(k1 >> 6) * 4096u + (k1 & 63));
    int k2 = k0 + 64;
    short8 b2 = *(const short8*)(wb + (unsigned)(k2 >> 6) * 4096u + (k2 & 63));
    int k3 = k0 + 96;
    short8 b3 = *(const short8*)(wb + (unsigned)(k3 >> 6) * 4096u + (k3 & 63));
    c0 = __builtin_amdgcn_mfma_f32_16x16x32_bf16(a0, b0, c0, 0, 0, 0);
    c1 = __builtin_amdgcn_mfma_f32_16x16x32_bf16(a1, b1, c1, 0, 0, 0);
    c2 = __builtin_amdgcn_mfma_f32_16x16x32_bf16(a2, b2, c2, 0, 0, 0);
    c3 = __builtin_amdgcn_mfma_f32_16x16x32_bf16(a3, b3, c3, 0, 0, 0);
  }
  f32x4 d;
#pragma unroll
  for (int j = 0; j < 4; ++j) d[j] = c0[j] + c1[j] + c2[j] + c3[j];

  // ---- epilogue: D[m=quad*4+reg][n=nt], col = wave*16+nt ----
  if (!fin) {
#pragma unroll
    for (int reg = 0; reg < 4; ++reg) {
      int row = row0 + quad * 4 + reg;
      embout[(unsigned)row * 64u + wave * 16 + nt] = f2bf(fmaxf(d[reg], 0.f));
    }
  } else {
    float v[4], sq[4];
#pragma unroll
    for (int reg = 0; reg < 4; ++reg) {
      v[reg] = fmaxf(d[reg], 0.f);
      sq[reg] = v[reg] * v[reg];
#pragma unroll
      for (int off = 8; off >= 1; off >>= 1)
        sq[reg] += __shfl_xor(sq[reg], off, 64);  // reduce over nt (16 lanes)
    }
    if (nt == 0) {
#pragma unroll
      for (int reg = 0; reg < 4; ++reg)
        ssp[wave * 16 + quad * 4 + reg] = sq[reg];
    }
    __syncthreads();
#pragma unroll
    for (int reg = 0; reg < 4; ++reg) {
      int m = quad * 4 + reg;
      float tot = ssp[m] + ssp[16 + m] + ssp[32 + m] + ssp[48 + m];
      float sc = 1.f / fmaxf(sqrtf(tot), 1e-12f);
      int row = row0 + m;
      finout[(unsigned)row * 64u + wave * 16 + nt] = v[reg] * sc;
    }
  }
}

extern "C" void kernel_launch(void* const* d_in, const int* in_sizes, int n_in,
                              void* d_out, int out_size, void* d_ws, size_t ws_size,
                              hipStream_t stream) {
  const float* x   = (const float*)d_in[0];
  const float* ent = (const float*)d_in[1];
  const float* rel = (const float*)d_in[2];
  const int* erow  = (const int*)d_in[3];
  const int* ecol  = (const int*)d_in[4];
  const float* ev  = (const float*)d_in[5];
  float* out = (float*)d_out;

  char* p = (char*)d_ws;
  ushort_t* emb_a = (ushort_t*)p;  p += (size_t)Nn * Dd * 2;          // 6.4 MB
  ushort_t* emb_b = (ushort_t*)p;  p += (size_t)Nn * Dd * 2;          // 6.4 MB
  ushort_t* wbf   = (ushort_t*)p;  p += (size_t)2 * Rr * Dd * Dd * 2; // 256 KB
  uint2* ed       = (uint2*)p;     p += (size_t)Rr * Ee * 8;          // 12.8 MB
  int* offs       = (int*)p;       p += (size_t)(Nn + 4) * 4;
  int* cnt        = (int*)p;       p += (size_t)Nn * 4;
  int* bsum       = (int*)p;       p += 256 * 4;

  // CSR build (shared by both layers)
  hipMemsetAsync(cnt, 0, (size_t)Nn * 4, stream);
  hist_k<<<dim3((Ee + 255) / 256, Rr), 256, 0, stream>>>(erow, cnt);
  scan1_k<<<SCAN_NB, 256, 0, stream>>>(cnt, bsum);
  scan2_k<<<1, 256, 0, stream>>>(bsum);
  scan3_k<<<SCAN_NB, 256, 0, stream>>>(cnt, bsum, offs);
  scatter_k<<<dim3((Ee + 255) / 256, Rr), 256, 0, stream>>>(erow, ecol, ev, cnt, ed);

  convw_k<<<(2 * Rr * Dd * Dd + 255) / 256, 256, 0, stream>>>(rel, wbf);
  init_gemm<<<(Nn + 3) / 4, 256, 0, stream>>>(x, ent, emb_a);

  // layer 1: emb_a -> emb_b (relu'd bf16)
  layer_k<<<Nn / 16, 256, 0, stream>>>(emb_a, wbf, offs, ed, emb_b, nullptr, 0);
  // layer 2: emb_b -> out (relu + L2 normalize, f32)
  layer_k<<<Nn / 16, 256, 0, stream>>>(emb_b, wbf + Rr * Dd * Dd, offs, ed,
                                       nullptr, out, 1);
}

// Round 4
// 621.661 us; speedup vs baseline: 2.5046x; 2.5046x over previous
//
#include <hip/hip_runtime.h>

#define Nn 50000
#define Rr 16
#define Dd 64
#define Fin 128
#define Ee 100000

typedef __attribute__((ext_vector_type(8))) short short8;
typedef __attribute__((ext_vector_type(4))) float f32x4;
typedef unsigned short ushort_t;

__device__ inline ushort_t f2bf(float x) {
  union { float f; unsigned u; } v; v.f = x;
  unsigned u = v.u;
  return (ushort_t)((u + 0x7FFFu + ((u >> 16) & 1u)) >> 16);  // RNE
}
__device__ inline float bf2f(ushort_t h) {
  union { unsigned u; float f; } v; v.u = ((unsigned)h) << 16; return v.f;
}

// ---------------- init: emb0 = x @ ent_emb, bf16 out ----------------
__global__ __launch_bounds__(256) void init_gemm(const float* __restrict__ x,
                                                 const float* __restrict__ w,
                                                 ushort_t* __restrict__ out) {
  int wave = threadIdx.x >> 6, lane = threadIdx.x & 63;
  int row = blockIdx.x * 4 + wave;
  if (row >= Nn) return;
  const float* xr = x + (long)row * Fin;
  float acc = 0.f;
#pragma unroll 8
  for (int k = 0; k < Fin; ++k)
    acc = fmaf(xr[k], w[k * Dd + lane], acc);
  out[row * Dd + lane] = f2bf(acc);
}

// ---------------- CSR build ----------------
__global__ __launch_bounds__(256) void hist_k(const int* __restrict__ erow,
                                              int* __restrict__ cnt) {
  int e = blockIdx.x * 256 + threadIdx.x;
  int r = blockIdx.y;
  if (e < Ee) atomicAdd(&cnt[erow[r * Ee + e]], 1);
}

// parallel scan, 3 kernels
#define SCAN_NB ((Nn + 255) / 256)  // 196
__global__ __launch_bounds__(256) void scan1_k(const int* __restrict__ cnt,
                                               int* __restrict__ bsum) {
  __shared__ int ls[256];
  int t = threadIdx.x, i = blockIdx.x * 256 + t;
  int v = (i < Nn) ? cnt[i] : 0;
  ls[t] = v;
  __syncthreads();
  for (int off = 128; off >= 1; off >>= 1) {
    if (t < off) ls[t] += ls[t + off];
    __syncthreads();
  }
  if (t == 0) bsum[blockIdx.x] = ls[0];
}

__global__ __launch_bounds__(256) void scan2_k(int* __restrict__ bsum) {
  __shared__ int ls[256];
  int t = threadIdx.x;
  int v = (t < SCAN_NB) ? bsum[t] : 0;
  ls[t] = v;
  __syncthreads();
  for (int off = 1; off < 256; off <<= 1) {
    int x = (t >= off) ? ls[t - off] : 0;
    __syncthreads();
    ls[t] += x;
    __syncthreads();
  }
  if (t < SCAN_NB) bsum[t] = ls[t] - v;  // exclusive
}

__global__ __launch_bounds__(256) void scan3_k(int* __restrict__ cnt,
                                               const int* __restrict__ bsum,
                                               int* __restrict__ offs) {
  __shared__ int ls[256];
  int t = threadIdx.x, i = blockIdx.x * 256 + t;
  int v = (i < Nn) ? cnt[i] : 0;
  ls[t] = v;
  __syncthreads();
  for (int off = 1; off < 256; off <<= 1) {
    int x = (t >= off) ? ls[t - off] : 0;
    __syncthreads();
    ls[t] += x;
    __syncthreads();
  }
  int excl = ls[t] - v + bsum[blockIdx.x];
  if (i < Nn) {
    offs[i] = excl;
    cnt[i] = excl;  // becomes cursor
  }
  if (i == Nn - 1) offs[Nn] = Rr * Ee;
}

__global__ __launch_bounds__(256) void scatter_k(const int* __restrict__ erow,
                                                 const int* __restrict__ ecol,
                                                 const float* __restrict__ ev,
                                                 int* __restrict__ cursor,
                                                 uint2* __restrict__ ed) {
  int e = blockIdx.x * 256 + threadIdx.x;
  int r = blockIdx.y;
  if (e >= Ee) return;
  long idx = (long)r * Ee + e;
  int row = erow[idx];
  int pos = atomicAdd(&cursor[row], 1);
  ed[pos] = make_uint2(((unsigned)r << 16) | (unsigned)ecol[idx],
                       __float_as_uint(ev[idx]));
}

// ---------------- W -> bf16 ----------------
__global__ __launch_bounds__(256) void convw_k(const float* __restrict__ rel,
                                               ushort_t* __restrict__ wbf) {
  int i = blockIdx.x * 256 + threadIdx.x;
  if (i < 2 * Rr * Dd * Dd) wbf[i] = f2bf(rel[i]);
}

// ---------------- Y_r = emb @ W_r^T for all r, bf16 out ----------------
__global__ __launch_bounds__(256) void ygemm_k(const ushort_t* __restrict__ emb,
                                               const ushort_t* __restrict__ wbf,
                                               ushort_t* __restrict__ Y) {
  int wave = threadIdx.x >> 6, lane = threadIdx.x & 63;
  int nt = lane & 15, quad = lane >> 4;
  int tile = blockIdx.x * 4 + wave;  // 16-row tile; Nn/16 = 3125 exact
  if (tile >= Nn / 16) return;

  const ushort_t* ar = emb + (unsigned)(tile * 16 + nt) * Dd + quad * 8;
  short8 a0 = *(const short8*)(ar);
  short8 a1 = *(const short8*)(ar + 32);

  for (int r = 0; r < Rr; ++r) {
    const ushort_t* wr = wbf + r * Dd * Dd;
    f32x4 acc[4];
#pragma unroll
    for (int dt = 0; dt < 4; ++dt) {
      const ushort_t* bp = wr + (unsigned)(dt * 16 + nt) * Dd + quad * 8;
      short8 b0 = *(const short8*)(bp);
      short8 b1 = *(const short8*)(bp + 32);
      f32x4 c = {0.f, 0.f, 0.f, 0.f};
      c = __builtin_amdgcn_mfma_f32_16x16x32_bf16(a0, b0, c, 0, 0, 0);
      c = __builtin_amdgcn_mfma_f32_16x16x32_bf16(a1, b1, c, 0, 0, 0);
      acc[dt] = c;
    }
    ushort_t* yr = Y + ((unsigned)r * Nn + (unsigned)tile * 16) * Dd;
#pragma unroll
    for (int dt = 0; dt < 4; ++dt)
#pragma unroll
      for (int reg = 0; reg < 4; ++reg)
        yr[(unsigned)(quad * 4 + reg) * Dd + dt * 16 + nt] = f2bf(acc[dt][reg]);
  }
}

// ---------------- gather: out[row] = sum_{edges->row} val * Y[rel][col] ------
__global__ __launch_bounds__(256) void gather_k(const ushort_t* __restrict__ Y,
                                                const int* __restrict__ offs,
                                                const uint2* __restrict__ ed,
                                                ushort_t* __restrict__ embout,
                                                float* __restrict__ finout,
                                                int fin) {
  int wave = threadIdx.x >> 6, lane = threadIdx.x & 63;
  int row = blockIdx.x * 4 + wave;
  if (row >= Nn) return;
  int s = offs[row], e = offs[row + 1];
  float accA = 0.f, accB = 0.f;
  int i = s;
  const int e8 = s + ((e - s) & ~7);
  for (; i < e8; i += 8) {
    uint2 q[8];
#pragma unroll
    for (int j = 0; j < 8; ++j) q[j] = ed[i + j];
    float y[8];
#pragma unroll
    for (int j = 0; j < 8; ++j)
      y[j] = bf2f(Y[((q[j].x >> 16) * (unsigned)Nn + (q[j].x & 0xFFFFu)) * 64u + lane]);
#pragma unroll
    for (int j = 0; j < 8; j += 2) {
      accA = fmaf(__uint_as_float(q[j].y), y[j], accA);
      accB = fmaf(__uint_as_float(q[j + 1].y), y[j + 1], accB);
    }
  }
  for (; i < e; ++i) {
    uint2 q = ed[i];
    accA = fmaf(__uint_as_float(q.y),
                bf2f(Y[((q.x >> 16) * (unsigned)Nn + (q.x & 0xFFFFu)) * 64u + lane]),
                accA);
  }
  float v = fmaxf(accA + accB, 0.f);
  if (fin) {
    float ss = v * v;
#pragma unroll
    for (int off = 32; off >= 1; off >>= 1) ss += __shfl_xor(ss, off, 64);
    finout[(unsigned)row * 64u + lane] = v / fmaxf(sqrtf(ss), 1e-12f);
  } else {
    embout[(unsigned)row * 64u + lane] = f2bf(v);
  }
}

extern "C" void kernel_launch(void* const* d_in, const int* in_sizes, int n_in,
                              void* d_out, int out_size, void* d_ws, size_t ws_size,
                              hipStream_t stream) {
  const float* x   = (const float*)d_in[0];
  const float* ent = (const float*)d_in[1];
  const float* rel = (const float*)d_in[2];
  const int* erow  = (const int*)d_in[3];
  const int* ecol  = (const int*)d_in[4];
  const float* ev  = (const float*)d_in[5];
  float* out = (float*)d_out;

  char* p = (char*)d_ws;
  ushort_t* emb_a = (ushort_t*)p;  p += (size_t)Nn * Dd * 2;           // 6.4 MB
  ushort_t* emb_b = (ushort_t*)p;  p += (size_t)Nn * Dd * 2;           // 6.4 MB
  ushort_t* wbf   = (ushort_t*)p;  p += (size_t)2 * Rr * Dd * Dd * 2;  // 256 KB
  ushort_t* Y     = (ushort_t*)p;  p += (size_t)Rr * Nn * Dd * 2;      // 102.4 MB
  uint2* ed       = (uint2*)p;     p += (size_t)Rr * Ee * 8;           // 12.8 MB
  int* offs       = (int*)p;       p += (size_t)(Nn + 4) * 4;
  int* cnt        = (int*)p;       p += (size_t)Nn * 4;
  int* bsum       = (int*)p;       p += 256 * 4;

  // CSR build (shared by both layers)
  hipMemsetAsync(cnt, 0, (size_t)Nn * 4, stream);
  hist_k<<<dim3((Ee + 255) / 256, Rr), 256, 0, stream>>>(erow, cnt);
  scan1_k<<<SCAN_NB, 256, 0, stream>>>(cnt, bsum);
  scan2_k<<<1, 256, 0, stream>>>(bsum);
  scan3_k<<<SCAN_NB, 256, 0, stream>>>(cnt, bsum, offs);
  scatter_k<<<dim3((Ee + 255) / 256, Rr), 256, 0, stream>>>(erow, ecol, ev, cnt, ed);

  convw_k<<<(2 * Rr * Dd * Dd + 255) / 256, 256, 0, stream>>>(rel, wbf);
  init_gemm<<<(Nn + 3) / 4, 256, 0, stream>>>(x, ent, emb_a);

  // layer 1
  ygemm_k<<<(Nn / 16 + 3) / 4, 256, 0, stream>>>(emb_a, wbf, Y);
  gather_k<<<(Nn + 3) / 4, 256, 0, stream>>>(Y, offs, ed, emb_b, nullptr, 0);
  // layer 2 (+ fused relu + L2 normalize)
  ygemm_k<<<(Nn / 16 + 3) / 4, 256, 0, stream>>>(emb_b, wbf + Rr * Dd * Dd, Y);
  gather_k<<<(Nn + 3) / 4, 256, 0, stream>>>(Y, offs, ed, nullptr, out, 1);
}